// Round 12
// baseline (47.727 us; speedup 1.0000x reference)
//
#include <hip/hip_runtime.h>
#include <hip/hip_bf16.h>

// Problem constants
#define NB    4
#define LQ    3840
#define NH    8
#define NL    4
#define NP    4
#define LIN   3840
#define NROWS (NB * LQ)     // 15360

typedef short          bf16x8 __attribute__((ext_vector_type(8)));
typedef float          f32x4  __attribute__((ext_vector_type(4)));
typedef unsigned short u16x8  __attribute__((ext_vector_type(8)));
typedef unsigned short u16x4  __attribute__((ext_vector_type(4)));

__device__ __forceinline__ unsigned short f2bf(float x) {
    __hip_bfloat16 h = __float2bfloat16(x);
    return *reinterpret_cast<unsigned short*>(&h);
}
__device__ __forceinline__ float bf2f(unsigned short u) {
    return __uint_as_float(((unsigned int)u) << 16);
}
__device__ __forceinline__ void gload_lds16(const unsigned short* g, unsigned short* l) {
    __builtin_amdgcn_global_load_lds(
        (const __attribute__((address_space(1))) unsigned int*)g,
        (__attribute__((address_space(3))) unsigned int*)l, 16, 0, 0);
}

// Swizzle convention (verified R3/R4): physical_byte = logical_byte ^ ((row&7)<<4),
// closed within each 128B k-slice. Fragment reads undo via ((l&7)<<4) since
// fragment row ≡ (l&15) mod 16 => row&7 == l&7.

// ---------------- convert + transpose weights -> swizzled bf16 [N][K] ----------------
__global__ __launch_bounds__(256) void convert_W(
    const float* __restrict__ Wv, const float* __restrict__ Wo,
    const float* __restrict__ Wa, const float* __restrict__ Wout,
    const float* __restrict__ bo, const float* __restrict__ ba,
    unsigned short* __restrict__ WvT, unsigned short* __restrict__ WcT,
    unsigned short* __restrict__ WoutT, float* __restrict__ bcat)
{
    const int n = blockIdx.x;    // output row (original col)
    const int k = threadIdx.x;
    const int idx = n * 256 + ((((2 * k) ^ ((n & 7) << 4))) >> 1);
    WvT[idx]   = f2bf(Wv[k * 256 + n]);
    WoutT[idx] = f2bf(Wout[k * 256 + n]);
    const float wc = (n < 128) ? Wo[k * 128 + n] : Wa[k * 128 + (n - 128)];
    WcT[idx] = f2bf(wc);
    if (k == 0) bcat[n] = (n < 128) ? bo[n] : ba[n - 128];
}

// ---------------- fused fwd GEMMs (BN=256, dedup A staging): z=0 valbf, z=1 offbf -------
// Tile 64x256, BK=64, 4 waves (2x2, wave tile 32x128). A f32 -> bf16 during
// reg-staging (done once per panel now). grid (240, 2).
__global__ __launch_bounds__(256) void gemm_fwd(
    const float* __restrict__ Ain, const float* __restrict__ Aq,
    const unsigned short* __restrict__ WvT, const unsigned short* __restrict__ WcT,
    const float* __restrict__ bval, const float* __restrict__ bcat,
    unsigned short* __restrict__ valbf, unsigned short* __restrict__ offbf)
{
    __shared__ unsigned short As[64 * 64];    //  8 KB
    __shared__ unsigned short Bs[256 * 64];   // 32 KB

    const int t  = threadIdx.x;
    const int l  = t & 63;
    const int w  = t >> 6;
    const int m0 = blockIdx.x * 64;
    const int z  = blockIdx.y;
    const int wm = w >> 1, wn = w & 1;

    const float* A           = z ? Aq  : Ain;
    const unsigned short* Bt = z ? WcT : WvT;

    f32x4 acc[2][8] = {};

    for (int k0 = 0; k0 < 256; k0 += 64) {
        // A: 64x64 f32 -> bf16, swizzled ds_write (once per panel — no x-dup)
        #pragma unroll
        for (int j = 0; j < 4; ++j) {
            const int e   = j * 256 + t;
            const int row = e >> 4;
            const int kq  = e & 15;
            const float4 v = *reinterpret_cast<const float4*>(
                A + (size_t)(m0 + row) * 256 + k0 + kq * 4);
            u16x4 r;
            r[0] = f2bf(v.x); r[1] = f2bf(v.y); r[2] = f2bf(v.z); r[3] = f2bf(v.w);
            const int byte = row * 128 + ((kq * 8) ^ ((row & 7) << 4));
            *reinterpret_cast<u16x4*>(&As[byte >> 1]) = r;
        }
        // B: 256 rows x 64 k, pre-swizzled source -> linear LDS
        #pragma unroll
        for (int j = 0; j < 8; ++j) {
            const int c    = w * 8 + j;
            const int rowB = c * 8 + (l >> 3);
            gload_lds16(Bt + (size_t)rowB * 256 + k0 + (l & 7) * 8, &Bs[c * 512]);
        }
        __syncthreads();

        #pragma unroll
        for (int kk = 0; kk < 2; ++kk) {
            const int koff = (kk * 64 + (l >> 4) * 16) ^ ((l & 7) << 4);
            bf16x8 af[2], bfr[8];
            #pragma unroll
            for (int mf = 0; mf < 2; ++mf) {
                const int row = wm * 32 + mf * 16 + (l & 15);
                af[mf] = *reinterpret_cast<const bf16x8*>(&As[row * 64 + (koff >> 1)]);
            }
            #pragma unroll
            for (int nf = 0; nf < 8; ++nf) {
                const int row = wn * 128 + nf * 16 + (l & 15);
                bfr[nf] = *reinterpret_cast<const bf16x8*>(&Bs[row * 64 + (koff >> 1)]);
            }
            #pragma unroll
            for (int mf = 0; mf < 2; ++mf)
                #pragma unroll
                for (int nf = 0; nf < 8; ++nf)
                    acc[mf][nf] = __builtin_amdgcn_mfma_f32_16x16x32_bf16(
                        af[mf], bfr[nf], acc[mf][nf], 0, 0, 0);
        }
        __syncthreads();
    }

    const float* bias = z ? bcat : bval;
    unsigned short* dst = z ? offbf : valbf;
    float bv[8];
    #pragma unroll
    for (int nf = 0; nf < 8; ++nf)
        bv[nf] = bias[wn * 128 + nf * 16 + (l & 15)];

    #pragma unroll
    for (int mf = 0; mf < 2; ++mf)
        #pragma unroll
        for (int nf = 0; nf < 8; ++nf) {
            const int col = wn * 128 + nf * 16 + (l & 15);
            #pragma unroll
            for (int q = 0; q < 4; ++q) {
                const int row = m0 + wm * 32 + mf * 16 + (l >> 4) * 4 + q;
                dst[(size_t)row * 256 + col] = f2bf(acc[mf][nf][q] + bv[nf]);
            }
        }
}

// ---------------- final GEMM (R8 structure + XCD swizzle): out = sampled @ WoutT + b_out -
__global__ __launch_bounds__(256) void gemm_out(
    const unsigned short* __restrict__ Abf,
    const unsigned short* __restrict__ Bt,
    const float* __restrict__ bias,
    float* __restrict__ C)
{
    __shared__ unsigned short As[64 * 64];
    __shared__ unsigned short Bs[128 * 64];

    const int t  = threadIdx.x;
    const int l  = t & 63;
    const int w  = t >> 6;

    // XCD-chunked bijective remap (nwg=480, 480%8==0)
    const int orig = blockIdx.x + 2 * blockIdx.y;
    const int p    = (orig & 7) * 60 + (orig >> 3);
    const int m0 = (p >> 1) * 64;
    const int n0 = (p & 1) * 128;
    const int wm = w >> 1, wn = w & 1;

    f32x4 acc[2][4] = {};

    for (int k0 = 0; k0 < 256; k0 += 64) {
        #pragma unroll
        for (int j = 0; j < 6; ++j) {               // 24 chunks: 8 A + 16 B
            const int c = w * 6 + j;
            if (c < 8) {
                const int rowA = c * 8 + (l >> 3);
                gload_lds16(Abf + (size_t)(m0 + rowA) * 256 + k0 + (l & 7) * 8,
                            &As[c * 512]);
            } else {
                const int cb   = c - 8;
                const int rowB = cb * 8 + (l >> 3);
                gload_lds16(Bt + (size_t)(n0 + rowB) * 256 + k0 + (l & 7) * 8,
                            &Bs[cb * 512]);
            }
        }
        __syncthreads();

        #pragma unroll
        for (int kk = 0; kk < 2; ++kk) {
            const int koff = (kk * 64 + (l >> 4) * 16) ^ ((l & 7) << 4);
            bf16x8 af[2], bfr[4];
            #pragma unroll
            for (int mf = 0; mf < 2; ++mf) {
                const int row = wm * 32 + mf * 16 + (l & 15);
                af[mf] = *reinterpret_cast<const bf16x8*>(&As[row * 64 + (koff >> 1)]);
            }
            #pragma unroll
            for (int nf = 0; nf < 4; ++nf) {
                const int row = wn * 64 + nf * 16 + (l & 15);
                bfr[nf] = *reinterpret_cast<const bf16x8*>(&Bs[row * 64 + (koff >> 1)]);
            }
            #pragma unroll
            for (int mf = 0; mf < 2; ++mf)
                #pragma unroll
                for (int nf = 0; nf < 4; ++nf)
                    acc[mf][nf] = __builtin_amdgcn_mfma_f32_16x16x32_bf16(
                        af[mf], bfr[nf], acc[mf][nf], 0, 0, 0);
        }
        __syncthreads();
    }

    float bv[4];
    #pragma unroll
    for (int nf = 0; nf < 4; ++nf)
        bv[nf] = bias[n0 + wn * 64 + nf * 16 + (l & 15)];

    #pragma unroll
    for (int mf = 0; mf < 2; ++mf)
        #pragma unroll
        for (int nf = 0; nf < 4; ++nf) {
            const int col = n0 + wn * 64 + nf * 16 + (l & 15);
            #pragma unroll
            for (int q = 0; q < 4; ++q) {
                const int row = m0 + wm * 32 + mf * 16 + (l >> 4) * 4 + q;
                C[(size_t)row * 256 + col] = acc[mf][nf][q] + bv[nf];
            }
        }
}

// ---------------- fused softmax + deformable sampling (R8, 16B gathers) ----------------
#define RPB 8

__global__ __launch_bounds__(256) void sample_k(
    const unsigned short* __restrict__ value, // [NB*LIN][256] bf16 linear
    const unsigned short* __restrict__ offbf, // [NROWS][256] bf16 linear
    const float* __restrict__ refp,
    const int*   __restrict__ shapes,
    const int*   __restrict__ starts,
    unsigned short* __restrict__ outbf)       // [NROWS][256] bf16, swizzled rows
{
    __shared__ unsigned short srow[RPB * 256];
    __shared__ float w0s[RPB * NH * 16];
    __shared__ float w1s[RPB * NH * 16];
    __shared__ int   a0s[RPB * NH * 16];
    __shared__ int   a1s[RPB * NH * 16];

    const int t  = threadIdx.x;
    const int b0 = blockIdx.x * RPB;
    const int nbase = (b0 / LQ) * LIN;        // block never straddles batch (8 | 3840)

    *reinterpret_cast<u16x8*>(&srow[t * 8]) =
        *reinterpret_cast<const u16x8*>(offbf + (size_t)b0 * 256 + t * 8);
    __syncthreads();

    const int r = t >> 5;          // 0..7
    const int h = (t >> 2) & 7;    // 0..7

    // ---- phase 1: (r,h,lvl) -> samples lvl*4 .. lvl*4+3 ----
    {
        const int lvl = t & 3;
        const int shp = shapes[lvl];
        const int stt = starts[lvl];
        const float T = (float)shp;
        const int Tm1 = shp - 1;

        const u16x4 lg4 = *reinterpret_cast<const u16x4*>(
            &srow[r * 256 + 128 + h * 16 + lvl * 4]);
        const u16x4 of4 = *reinterpret_cast<const u16x4*>(
            &srow[r * 256 + h * 16 + lvl * 4]);
        float lg[4], e[4];
        #pragma unroll
        for (int u = 0; u < 4; ++u) lg[u] = bf2f(lg4[u]);

        float mx = fmaxf(fmaxf(lg[0], lg[1]), fmaxf(lg[2], lg[3]));
        mx = fmaxf(mx, __shfl_xor(mx, 1));
        mx = fmaxf(mx, __shfl_xor(mx, 2));
        float sum = 0.f;
        #pragma unroll
        for (int u = 0; u < 4; ++u) { e[u] = __expf(lg[u] - mx); sum += e[u]; }
        sum += __shfl_xor(sum, 1);
        sum += __shfl_xor(sum, 2);
        const float rsum = 1.f / sum;

        const float ref = refp[(size_t)(b0 + r) * NL + lvl];
        #pragma unroll
        for (int u = 0; u < 4; ++u) {
            const float aw  = e[u] * rsum;
            const float off = bf2f(of4[u]);
            const float loc = ref + off / T;     // mimic reference rounding
            const float cc  = loc * T - 0.5f;
            const float fl  = floorf(cc);
            const float wgt = cc - fl;
            const int i0 = (int)fl;
            const int j0 = min(max(i0, 0), Tm1);
            const int j1 = min(max(i0 + 1, 0), Tm1);
            const int idx = (r * 8 + h) * 16 + lvl * 4 + u;
            w0s[idx] = aw * (1.f - wgt);
            w1s[idx] = aw * wgt;
            a0s[idx] = nbase + stt + j0;
            a1s[idx] = nbase + stt + j1;
        }
    }
    __syncthreads();

    // ---- phase 2: (r,h,d2) -> 8 output dims, 32 gathers of 16B ----
    {
        const int d2   = t & 3;
        const int coff = h * 32 + d2 * 8;        // ushort offset within value row
        const int base = (r * 8 + h) * 16;

        float acc[8] = {};
        #pragma unroll
        for (int s = 0; s < 16; ++s) {
            const float w0 = w0s[base + s];
            const float w1 = w1s[base + s];
            const u16x8 v0 = *reinterpret_cast<const u16x8*>(
                value + (size_t)a0s[base + s] * 256 + coff);
            const u16x8 v1 = *reinterpret_cast<const u16x8*>(
                value + (size_t)a1s[base + s] * 256 + coff);
            #pragma unroll
            for (int q = 0; q < 8; ++q)
                acc[q] += w0 * bf2f(v0[q]) + w1 * bf2f(v1[q]);
        }
        const int orow = b0 + r;
        u16x8 o;
        #pragma unroll
        for (int q = 0; q < 8; ++q) o[q] = f2bf(acc[q]);
        const int byte = (h * 64 + d2 * 16) ^ ((orow & 7) << 4);   // within 512B row
        *reinterpret_cast<u16x8*>(&outbf[(size_t)orow * 256 + (byte >> 1)]) = o;
    }
}

extern "C" void kernel_launch(void* const* d_in, const int* in_sizes, int n_in,
                              void* d_out, int out_size, void* d_ws, size_t ws_size,
                              hipStream_t stream) {
    const float* query  = (const float*)d_in[0];
    const float* refp   = (const float*)d_in[1];
    const float* inflat = (const float*)d_in[2];
    const int*   shapes = (const int*)d_in[3];
    const int*   starts = (const int*)d_in[4];
    const float* W_off  = (const float*)d_in[5];
    const float* b_off  = (const float*)d_in[6];
    const float* W_attn = (const float*)d_in[7];
    const float* b_attn = (const float*)d_in[8];
    const float* W_val  = (const float*)d_in[9];
    const float* b_val  = (const float*)d_in[10];
    const float* W_out  = (const float*)d_in[11];
    const float* b_out  = (const float*)d_in[12];
    float* out = (float*)d_out;

    // ws layout
    char* ws = (char*)d_ws;
    const size_t BFMAT = (size_t)NROWS * 256 * 2;    // 7.9 MB
    unsigned short* valbf = (unsigned short*)ws;
    unsigned short* offbf = (unsigned short*)(ws + BFMAT);
    unsigned short* outbf = (unsigned short*)(ws + 2 * BFMAT);
    unsigned short* WvT   = (unsigned short*)(ws + 3 * BFMAT);
    unsigned short* WcT   = WvT + 65536;
    unsigned short* WoutT = WcT + 65536;
    float*          bcat  = (float*)(WoutT + 65536);

    const dim3 blk(256);

    convert_W<<<256, blk, 0, stream>>>(W_val, W_off, W_attn, W_out, b_off, b_attn,
                                       WvT, WcT, WoutT, bcat);
    // z=0: valbf = inflat@WvT+b_val ; z=1: offbf = query@WcT+bcat   (both bf16)
    gemm_fwd<<<dim3(240, 2), blk, 0, stream>>>(inflat, query, WvT, WcT,
                                               b_val, bcat, valbf, offbf);
    sample_k<<<NROWS / RPB, blk, 0, stream>>>(valbf, offbf, refp, shapes, starts, outbf);
    gemm_out<<<dim3(2, 240), blk, 0, stream>>>(outbf, WoutT, b_out, out);
}

// Round 13
// 45.256 us; speedup vs baseline: 1.0546x; 1.0546x over previous
//
#include <hip/hip_runtime.h>
#include <hip/hip_bf16.h>

// Problem constants
#define NB    4
#define LQ    3840
#define NH    8
#define NL    4
#define NP    4
#define LIN   3840
#define NROWS (NB * LQ)     // 15360

typedef short          bf16x8 __attribute__((ext_vector_type(8)));
typedef float          f32x4  __attribute__((ext_vector_type(4)));
typedef unsigned short u16x8  __attribute__((ext_vector_type(8)));
typedef unsigned short u16x4  __attribute__((ext_vector_type(4)));

__device__ __forceinline__ unsigned short f2bf(float x) {
    __hip_bfloat16 h = __float2bfloat16(x);
    return *reinterpret_cast<unsigned short*>(&h);
}
__device__ __forceinline__ float bf2f(unsigned short u) {
    return __uint_as_float(((unsigned int)u) << 16);
}
__device__ __forceinline__ void gload_lds16(const unsigned short* g, unsigned short* l) {
    __builtin_amdgcn_global_load_lds(
        (const __attribute__((address_space(1))) unsigned int*)g,
        (__attribute__((address_space(3))) unsigned int*)l, 16, 0, 0);
}

// Swizzle convention (verified R3/R4): physical_byte = logical_byte ^ ((row&7)<<4),
// closed within each 128B k-slice. Fragment reads undo via ((l&7)<<4) since
// fragment row ≡ (l&15) mod 16 => row&7 == l&7.

// ---------------- convert + transpose weights -> swizzled bf16 [N][K] ----------------
__global__ __launch_bounds__(256) void convert_W(
    const float* __restrict__ Wv, const float* __restrict__ Wo,
    const float* __restrict__ Wa, const float* __restrict__ Wout,
    const float* __restrict__ bo, const float* __restrict__ ba,
    unsigned short* __restrict__ WvT, unsigned short* __restrict__ WcT,
    unsigned short* __restrict__ WoutT, float* __restrict__ bcat)
{
    const int n = blockIdx.x;    // output row (original col)
    const int k = threadIdx.x;
    const int idx = n * 256 + ((((2 * k) ^ ((n & 7) << 4))) >> 1);
    WvT[idx]   = f2bf(Wv[k * 256 + n]);
    WoutT[idx] = f2bf(Wout[k * 256 + n]);
    const float wc = (n < 128) ? Wo[k * 128 + n] : Wa[k * 128 + (n - 128)];
    WcT[idx] = f2bf(wc);
    if (k == 0) bcat[n] = (n < 128) ? bo[n] : ba[n - 128];
}

// ---------------- fused fwd GEMMs (R11: 64x128 tile + XCD swizzle): z=0 valbf, z=1 offbf -
__global__ __launch_bounds__(256) void gemm_fwd(
    const float* __restrict__ Ain, const float* __restrict__ Aq,
    const unsigned short* __restrict__ WvT, const unsigned short* __restrict__ WcT,
    const float* __restrict__ bval, const float* __restrict__ bcat,
    unsigned short* __restrict__ valbf, unsigned short* __restrict__ offbf)
{
    __shared__ unsigned short As[64 * 64];
    __shared__ unsigned short Bs[128 * 64];

    const int t  = threadIdx.x;
    const int l  = t & 63;
    const int w  = t >> 6;

    // XCD-chunked bijective remap (nwg=960, 960%8==0)
    const int orig = blockIdx.x + 2 * (blockIdx.y + 240 * blockIdx.z);
    const int p    = (orig & 7) * 120 + (orig >> 3);
    const int m0 = ((p >> 1) % 240) * 64;
    const int n0 = (p & 1) * 128;
    const int z  = p / 480;
    const int wm = w >> 1, wn = w & 1;

    const float* A           = z ? Aq  : Ain;
    const unsigned short* Bt = z ? WcT : WvT;

    f32x4 acc[2][4] = {};

    for (int k0 = 0; k0 < 256; k0 += 64) {
        #pragma unroll
        for (int j = 0; j < 4; ++j) {
            const int e   = j * 256 + t;
            const int row = e >> 4;
            const int kq  = e & 15;
            const float4 v = *reinterpret_cast<const float4*>(
                A + (size_t)(m0 + row) * 256 + k0 + kq * 4);
            u16x4 r;
            r[0] = f2bf(v.x); r[1] = f2bf(v.y); r[2] = f2bf(v.z); r[3] = f2bf(v.w);
            const int byte = row * 128 + ((kq * 8) ^ ((row & 7) << 4));
            *reinterpret_cast<u16x4*>(&As[byte >> 1]) = r;
        }
        #pragma unroll
        for (int j = 0; j < 4; ++j) {
            const int c    = w * 4 + j;
            const int rowB = c * 8 + (l >> 3);
            gload_lds16(Bt + (size_t)(n0 + rowB) * 256 + k0 + (l & 7) * 8, &Bs[c * 512]);
        }
        __syncthreads();

        #pragma unroll
        for (int kk = 0; kk < 2; ++kk) {
            const int koff = (kk * 64 + (l >> 4) * 16) ^ ((l & 7) << 4);
            bf16x8 af[2], bfr[4];
            #pragma unroll
            for (int mf = 0; mf < 2; ++mf) {
                const int row = wm * 32 + mf * 16 + (l & 15);
                af[mf] = *reinterpret_cast<const bf16x8*>(&As[row * 64 + (koff >> 1)]);
            }
            #pragma unroll
            for (int nf = 0; nf < 4; ++nf) {
                const int row = wn * 64 + nf * 16 + (l & 15);
                bfr[nf] = *reinterpret_cast<const bf16x8*>(&Bs[row * 64 + (koff >> 1)]);
            }
            #pragma unroll
            for (int mf = 0; mf < 2; ++mf)
                #pragma unroll
                for (int nf = 0; nf < 4; ++nf)
                    acc[mf][nf] = __builtin_amdgcn_mfma_f32_16x16x32_bf16(
                        af[mf], bfr[nf], acc[mf][nf], 0, 0, 0);
        }
        __syncthreads();
    }

    const float* bias = z ? bcat : bval;
    unsigned short* dst = z ? offbf : valbf;
    float bv[4];
    #pragma unroll
    for (int nf = 0; nf < 4; ++nf)
        bv[nf] = bias[n0 + wn * 64 + nf * 16 + (l & 15)];

    #pragma unroll
    for (int mf = 0; mf < 2; ++mf)
        #pragma unroll
        for (int nf = 0; nf < 4; ++nf) {
            const int col = n0 + wn * 64 + nf * 16 + (l & 15);
            #pragma unroll
            for (int q = 0; q < 4; ++q) {
                const int row = m0 + wm * 32 + mf * 16 + (l >> 4) * 4 + q;
                dst[(size_t)row * 256 + col] = f2bf(acc[mf][nf][q] + bv[nf]);
            }
        }
}

// ---------------- final GEMM (R11: R8 structure + XCD swizzle) ----------------
__global__ __launch_bounds__(256) void gemm_out(
    const unsigned short* __restrict__ Abf,
    const unsigned short* __restrict__ Bt,
    const float* __restrict__ bias,
    float* __restrict__ C)
{
    __shared__ unsigned short As[64 * 64];
    __shared__ unsigned short Bs[128 * 64];

    const int t  = threadIdx.x;
    const int l  = t & 63;
    const int w  = t >> 6;

    // XCD-chunked bijective remap (nwg=480, 480%8==0)
    const int orig = blockIdx.x + 2 * blockIdx.y;
    const int p    = (orig & 7) * 60 + (orig >> 3);
    const int m0 = (p >> 1) * 64;
    const int n0 = (p & 1) * 128;
    const int wm = w >> 1, wn = w & 1;

    f32x4 acc[2][4] = {};

    for (int k0 = 0; k0 < 256; k0 += 64) {
        #pragma unroll
        for (int j = 0; j < 6; ++j) {               // 24 chunks: 8 A + 16 B
            const int c = w * 6 + j;
            if (c < 8) {
                const int rowA = c * 8 + (l >> 3);
                gload_lds16(Abf + (size_t)(m0 + rowA) * 256 + k0 + (l & 7) * 8,
                            &As[c * 512]);
            } else {
                const int cb   = c - 8;
                const int rowB = cb * 8 + (l >> 3);
                gload_lds16(Bt + (size_t)(n0 + rowB) * 256 + k0 + (l & 7) * 8,
                            &Bs[cb * 512]);
            }
        }
        __syncthreads();

        #pragma unroll
        for (int kk = 0; kk < 2; ++kk) {
            const int koff = (kk * 64 + (l >> 4) * 16) ^ ((l & 7) << 4);
            bf16x8 af[2], bfr[4];
            #pragma unroll
            for (int mf = 0; mf < 2; ++mf) {
                const int row = wm * 32 + mf * 16 + (l & 15);
                af[mf] = *reinterpret_cast<const bf16x8*>(&As[row * 64 + (koff >> 1)]);
            }
            #pragma unroll
            for (int nf = 0; nf < 4; ++nf) {
                const int row = wn * 64 + nf * 16 + (l & 15);
                bfr[nf] = *reinterpret_cast<const bf16x8*>(&Bs[row * 64 + (koff >> 1)]);
            }
            #pragma unroll
            for (int mf = 0; mf < 2; ++mf)
                #pragma unroll
                for (int nf = 0; nf < 4; ++nf)
                    acc[mf][nf] = __builtin_amdgcn_mfma_f32_16x16x32_bf16(
                        af[mf], bfr[nf], acc[mf][nf], 0, 0, 0);
        }
        __syncthreads();
    }

    float bv[4];
    #pragma unroll
    for (int nf = 0; nf < 4; ++nf)
        bv[nf] = bias[n0 + wn * 64 + nf * 16 + (l & 15)];

    #pragma unroll
    for (int mf = 0; mf < 2; ++mf)
        #pragma unroll
        for (int nf = 0; nf < 4; ++nf) {
            const int col = n0 + wn * 64 + nf * 16 + (l & 15);
            #pragma unroll
            for (int q = 0; q < 4; ++q) {
                const int row = m0 + wm * 32 + mf * 16 + (l >> 4) * 4 + q;
                C[(size_t)row * 256 + col] = acc[mf][nf][q] + bv[nf];
            }
        }
}

// ---------------- fused softmax + deformable sampling (shfl phase-exchange) -------------
// 8 rows/block, 1920 blocks. Phase 1: (r,h,lvl) computes its level's 4 samples into
// REGISTERS; phase 2: (r,h,d2) pulls each sample's {w0,w1,a0,a1} from its quad-mate
// via __shfl (same 4-lane group) — no LDS arrays, no second barrier.
#define RPB 8

__global__ __launch_bounds__(256) void sample_k(
    const unsigned short* __restrict__ value, // [NB*LIN][256] bf16 linear
    const unsigned short* __restrict__ offbf, // [NROWS][256] bf16 linear
    const float* __restrict__ refp,
    const int*   __restrict__ shapes,
    const int*   __restrict__ starts,
    unsigned short* __restrict__ outbf)       // [NROWS][256] bf16, swizzled rows
{
    __shared__ unsigned short srow[RPB * 256];   // 4KB only

    const int t  = threadIdx.x;
    const int b0 = blockIdx.x * RPB;
    const int nbase = (b0 / LQ) * LIN;        // block never straddles batch (8 | 3840)

    *reinterpret_cast<u16x8*>(&srow[t * 8]) =
        *reinterpret_cast<const u16x8*>(offbf + (size_t)b0 * 256 + t * 8);
    __syncthreads();

    const int r = t >> 5;          // 0..7
    const int h = (t >> 2) & 7;    // 0..7

    // ---- phase 1: (r,h,lvl) -> this level's 4 samples, kept in registers ----
    float w0r[4], w1r[4];
    int   a0r[4], a1r[4];
    {
        const int lvl = t & 3;
        const int shp = shapes[lvl];
        const int stt = starts[lvl];
        const float T = (float)shp;
        const int Tm1 = shp - 1;

        const u16x4 lg4 = *reinterpret_cast<const u16x4*>(
            &srow[r * 256 + 128 + h * 16 + lvl * 4]);
        const u16x4 of4 = *reinterpret_cast<const u16x4*>(
            &srow[r * 256 + h * 16 + lvl * 4]);
        float lg[4], e[4];
        #pragma unroll
        for (int u = 0; u < 4; ++u) lg[u] = bf2f(lg4[u]);

        float mx = fmaxf(fmaxf(lg[0], lg[1]), fmaxf(lg[2], lg[3]));
        mx = fmaxf(mx, __shfl_xor(mx, 1));
        mx = fmaxf(mx, __shfl_xor(mx, 2));
        float sum = 0.f;
        #pragma unroll
        for (int u = 0; u < 4; ++u) { e[u] = __expf(lg[u] - mx); sum += e[u]; }
        sum += __shfl_xor(sum, 1);
        sum += __shfl_xor(sum, 2);
        const float rsum = 1.f / sum;

        const float ref = refp[(size_t)(b0 + r) * NL + lvl];
        #pragma unroll
        for (int u = 0; u < 4; ++u) {
            const float aw  = e[u] * rsum;
            const float off = bf2f(of4[u]);
            const float loc = ref + off / T;     // mimic reference rounding
            const float cc  = loc * T - 0.5f;
            const float fl  = floorf(cc);
            const float wgt = cc - fl;
            const int i0 = (int)fl;
            const int j0 = min(max(i0, 0), Tm1);
            const int j1 = min(max(i0 + 1, 0), Tm1);
            w0r[u] = aw * (1.f - wgt);
            w1r[u] = aw * wgt;
            a0r[u] = nbase + stt + j0;
            a1r[u] = nbase + stt + j1;
        }
    }
    // no barrier: exchange happens within the 4-lane quad via shfl

    // ---- phase 2: (r,h,d2) -> 8 output dims, 32 gathers of 16B ----
    {
        const int d2    = t & 3;
        const int coff  = h * 32 + d2 * 8;       // ushort offset within value row
        const int lquad = (t & 63) & ~3;         // quad base lane within wave

        float acc[8] = {};
        #pragma unroll
        for (int s = 0; s < 16; ++s) {
            const int src = lquad | (s >> 2);    // quad-mate holding level s>>2
            const float w0 = __shfl(w0r[s & 3], src);
            const float w1 = __shfl(w1r[s & 3], src);
            const int   i0 = __shfl(a0r[s & 3], src);
            const int   i1 = __shfl(a1r[s & 3], src);
            const u16x8 v0 = *reinterpret_cast<const u16x8*>(
                value + (size_t)i0 * 256 + coff);
            const u16x8 v1 = *reinterpret_cast<const u16x8*>(
                value + (size_t)i1 * 256 + coff);
            #pragma unroll
            for (int q = 0; q < 8; ++q)
                acc[q] += w0 * bf2f(v0[q]) + w1 * bf2f(v1[q]);
        }
        const int orow = b0 + r;
        u16x8 o;
        #pragma unroll
        for (int q = 0; q < 8; ++q) o[q] = f2bf(acc[q]);
        const int byte = (h * 64 + d2 * 16) ^ ((orow & 7) << 4);   // within 512B row
        *reinterpret_cast<u16x8*>(&outbf[(size_t)orow * 256 + (byte >> 1)]) = o;
    }
}

extern "C" void kernel_launch(void* const* d_in, const int* in_sizes, int n_in,
                              void* d_out, int out_size, void* d_ws, size_t ws_size,
                              hipStream_t stream) {
    const float* query  = (const float*)d_in[0];
    const float* refp   = (const float*)d_in[1];
    const float* inflat = (const float*)d_in[2];
    const int*   shapes = (const int*)d_in[3];
    const int*   starts = (const int*)d_in[4];
    const float* W_off  = (const float*)d_in[5];
    const float* b_off  = (const float*)d_in[6];
    const float* W_attn = (const float*)d_in[7];
    const float* b_attn = (const float*)d_in[8];
    const float* W_val  = (const float*)d_in[9];
    const float* b_val  = (const float*)d_in[10];
    const float* W_out  = (const float*)d_in[11];
    const float* b_out  = (const float*)d_in[12];
    float* out = (float*)d_out;

    // ws layout
    char* ws = (char*)d_ws;
    const size_t BFMAT = (size_t)NROWS * 256 * 2;    // 7.9 MB
    unsigned short* valbf = (unsigned short*)ws;
    unsigned short* offbf = (unsigned short*)(ws + BFMAT);
    unsigned short* outbf = (unsigned short*)(ws + 2 * BFMAT);
    unsigned short* WvT   = (unsigned short*)(ws + 3 * BFMAT);
    unsigned short* WcT   = WvT + 65536;
    unsigned short* WoutT = WcT + 65536;
    float*          bcat  = (float*)(WoutT + 65536);

    const dim3 blk(256);

    convert_W<<<256, blk, 0, stream>>>(W_val, W_off, W_attn, W_out, b_off, b_attn,
                                       WvT, WcT, WoutT, bcat);
    // z=0: valbf = inflat@WvT+b_val ; z=1: offbf = query@WcT+bcat   (both bf16)
    gemm_fwd<<<dim3(2, 240, 2), blk, 0, stream>>>(inflat, query, WvT, WcT,
                                                  b_val, bcat, valbf, offbf);
    sample_k<<<NROWS / RPB, blk, 0, stream>>>(valbf, offbf, refp, shapes, starts, outbf);
    gemm_out<<<dim3(2, 240), blk, 0, stream>>>(outbf, WoutT, b_out, out);
}

// Round 14
// 44.478 us; speedup vs baseline: 1.0730x; 1.0175x over previous
//
#include <hip/hip_runtime.h>
#include <hip/hip_bf16.h>

// Problem constants
#define NB    4
#define LQ    3840
#define NH    8
#define NL    4
#define NP    4
#define LIN   3840
#define NROWS (NB * LQ)     // 15360

typedef short          bf16x8 __attribute__((ext_vector_type(8)));
typedef float          f32x4  __attribute__((ext_vector_type(4)));
typedef unsigned short u16x8  __attribute__((ext_vector_type(8)));
typedef unsigned short u16x4  __attribute__((ext_vector_type(4)));

__device__ __forceinline__ unsigned short f2bf(float x) {
    __hip_bfloat16 h = __float2bfloat16(x);
    return *reinterpret_cast<unsigned short*>(&h);
}
__device__ __forceinline__ float bf2f(unsigned short u) {
    return __uint_as_float(((unsigned int)u) << 16);
}
__device__ __forceinline__ void gload_lds16(const unsigned short* g, unsigned short* l) {
    __builtin_amdgcn_global_load_lds(
        (const __attribute__((address_space(1))) unsigned int*)g,
        (__attribute__((address_space(3))) unsigned int*)l, 16, 0, 0);
}

// Swizzle convention (verified R3/R4): physical_byte = logical_byte ^ ((row&7)<<4),
// closed within each 128B k-slice. Fragment reads undo via ((l&7)<<4) since
// fragment row ≡ (l&15) mod 16 => row&7 == l&7.

// ---------------- convert + transpose weights (coalesced LDS-transpose) ----------------
// 48 blocks: x = tile (4 col-tiles x 4 row-tiles), y = matrix {0:Wv,1:Wcat,2:Wout}.
// Reads 64x64 f32 coalesced, transposes via padded LDS, writes swizzled bf16 coalesced.
__global__ __launch_bounds__(256) void convert_W(
    const float* __restrict__ Wv, const float* __restrict__ Wo,
    const float* __restrict__ Wa, const float* __restrict__ Wout,
    const float* __restrict__ bo, const float* __restrict__ ba,
    unsigned short* __restrict__ WvT, unsigned short* __restrict__ WcT,
    unsigned short* __restrict__ WoutT, float* __restrict__ bcat)
{
    __shared__ float tile[64][65];

    const int t   = threadIdx.x;
    const int mat = blockIdx.y;
    const int tx  = blockIdx.x & 3;     // col-tile (n-block)
    const int ty  = blockIdx.x >> 2;    // row-tile (k-block)
    const int n0  = tx * 64;
    const int k0  = ty * 64;

    // read 64x64 f32, coalesced float4
    #pragma unroll
    for (int j = 0; j < 4; ++j) {
        const int idx = j * 256 + t;
        const int r   = idx >> 4;           // 0..63  (k-local)
        const int c4  = (idx & 15) * 4;     // 0..60  (n-local)
        const int row = k0 + r;
        const int col = n0 + c4;
        float4 v;
        if (mat == 0)      v = *reinterpret_cast<const float4*>(Wv   + (size_t)row * 256 + col);
        else if (mat == 2) v = *reinterpret_cast<const float4*>(Wout + (size_t)row * 256 + col);
        else {
            if (col < 128) v = *reinterpret_cast<const float4*>(Wo + (size_t)row * 128 + col);
            else           v = *reinterpret_cast<const float4*>(Wa + (size_t)row * 128 + (col - 128));
        }
        tile[r][c4 + 0] = v.x; tile[r][c4 + 1] = v.y;
        tile[r][c4 + 2] = v.z; tile[r][c4 + 3] = v.w;
    }
    __syncthreads();

    unsigned short* WT = (mat == 0) ? WvT : (mat == 1) ? WcT : WoutT;

    // write: n-major, 4 k per thread-iter, coalesced u16x4 (swizzle permutes within 128B)
    #pragma unroll
    for (int j = 0; j < 4; ++j) {
        const int idx = j * 256 + t;
        const int nl  = idx >> 4;           // 0..63 n-local
        const int kq  = idx & 15;           // 0..15 (4-k chunk)
        const int n   = n0 + nl;
        const int k4  = kq * 4;             // k-local base
        u16x4 r;
        r[0] = f2bf(tile[k4 + 0][nl]); r[1] = f2bf(tile[k4 + 1][nl]);
        r[2] = f2bf(tile[k4 + 2][nl]); r[3] = f2bf(tile[k4 + 3][nl]);
        const int byte = (2 * (k0 + k4)) ^ ((n & 7) << 4);
        *reinterpret_cast<u16x4*>(&WT[n * 256 + (byte >> 1)]) = r;
    }

    if (mat == 1 && blockIdx.x == 0)
        bcat[t] = (t < 128) ? bo[t] : ba[t - 128];
}

// ---------------- fused fwd GEMMs (R11: 64x128 tile + XCD swizzle): z=0 valbf, z=1 offbf -
__global__ __launch_bounds__(256) void gemm_fwd(
    const float* __restrict__ Ain, const float* __restrict__ Aq,
    const unsigned short* __restrict__ WvT, const unsigned short* __restrict__ WcT,
    const float* __restrict__ bval, const float* __restrict__ bcat,
    unsigned short* __restrict__ valbf, unsigned short* __restrict__ offbf)
{
    __shared__ unsigned short As[64 * 64];
    __shared__ unsigned short Bs[128 * 64];

    const int t  = threadIdx.x;
    const int l  = t & 63;
    const int w  = t >> 6;

    // XCD-chunked bijective remap (nwg=960, 960%8==0)
    const int orig = blockIdx.x + 2 * (blockIdx.y + 240 * blockIdx.z);
    const int p    = (orig & 7) * 120 + (orig >> 3);
    const int m0 = ((p >> 1) % 240) * 64;
    const int n0 = (p & 1) * 128;
    const int z  = p / 480;
    const int wm = w >> 1, wn = w & 1;

    const float* A           = z ? Aq  : Ain;
    const unsigned short* Bt = z ? WcT : WvT;

    f32x4 acc[2][4] = {};

    for (int k0 = 0; k0 < 256; k0 += 64) {
        #pragma unroll
        for (int j = 0; j < 4; ++j) {
            const int e   = j * 256 + t;
            const int row = e >> 4;
            const int kq  = e & 15;
            const float4 v = *reinterpret_cast<const float4*>(
                A + (size_t)(m0 + row) * 256 + k0 + kq * 4);
            u16x4 r;
            r[0] = f2bf(v.x); r[1] = f2bf(v.y); r[2] = f2bf(v.z); r[3] = f2bf(v.w);
            const int byte = row * 128 + ((kq * 8) ^ ((row & 7) << 4));
            *reinterpret_cast<u16x4*>(&As[byte >> 1]) = r;
        }
        #pragma unroll
        for (int j = 0; j < 4; ++j) {
            const int c    = w * 4 + j;
            const int rowB = c * 8 + (l >> 3);
            gload_lds16(Bt + (size_t)(n0 + rowB) * 256 + k0 + (l & 7) * 8, &Bs[c * 512]);
        }
        __syncthreads();

        #pragma unroll
        for (int kk = 0; kk < 2; ++kk) {
            const int koff = (kk * 64 + (l >> 4) * 16) ^ ((l & 7) << 4);
            bf16x8 af[2], bfr[4];
            #pragma unroll
            for (int mf = 0; mf < 2; ++mf) {
                const int row = wm * 32 + mf * 16 + (l & 15);
                af[mf] = *reinterpret_cast<const bf16x8*>(&As[row * 64 + (koff >> 1)]);
            }
            #pragma unroll
            for (int nf = 0; nf < 4; ++nf) {
                const int row = wn * 64 + nf * 16 + (l & 15);
                bfr[nf] = *reinterpret_cast<const bf16x8*>(&Bs[row * 64 + (koff >> 1)]);
            }
            #pragma unroll
            for (int mf = 0; mf < 2; ++mf)
                #pragma unroll
                for (int nf = 0; nf < 4; ++nf)
                    acc[mf][nf] = __builtin_amdgcn_mfma_f32_16x16x32_bf16(
                        af[mf], bfr[nf], acc[mf][nf], 0, 0, 0);
        }
        __syncthreads();
    }

    const float* bias = z ? bcat : bval;
    unsigned short* dst = z ? offbf : valbf;
    float bv[4];
    #pragma unroll
    for (int nf = 0; nf < 4; ++nf)
        bv[nf] = bias[n0 + wn * 64 + nf * 16 + (l & 15)];

    #pragma unroll
    for (int mf = 0; mf < 2; ++mf)
        #pragma unroll
        for (int nf = 0; nf < 4; ++nf) {
            const int col = n0 + wn * 64 + nf * 16 + (l & 15);
            #pragma unroll
            for (int q = 0; q < 4; ++q) {
                const int row = m0 + wm * 32 + mf * 16 + (l >> 4) * 4 + q;
                dst[(size_t)row * 256 + col] = f2bf(acc[mf][nf][q] + bv[nf]);
            }
        }
}

// ---------------- final GEMM (R11: R8 structure + XCD swizzle) ----------------
__global__ __launch_bounds__(256) void gemm_out(
    const unsigned short* __restrict__ Abf,
    const unsigned short* __restrict__ Bt,
    const float* __restrict__ bias,
    float* __restrict__ C)
{
    __shared__ unsigned short As[64 * 64];
    __shared__ unsigned short Bs[128 * 64];

    const int t  = threadIdx.x;
    const int l  = t & 63;
    const int w  = t >> 6;

    // XCD-chunked bijective remap (nwg=480, 480%8==0)
    const int orig = blockIdx.x + 2 * blockIdx.y;
    const int p    = (orig & 7) * 60 + (orig >> 3);
    const int m0 = (p >> 1) * 64;
    const int n0 = (p & 1) * 128;
    const int wm = w >> 1, wn = w & 1;

    f32x4 acc[2][4] = {};

    for (int k0 = 0; k0 < 256; k0 += 64) {
        #pragma unroll
        for (int j = 0; j < 6; ++j) {               // 24 chunks: 8 A + 16 B
            const int c = w * 6 + j;
            if (c < 8) {
                const int rowA = c * 8 + (l >> 3);
                gload_lds16(Abf + (size_t)(m0 + rowA) * 256 + k0 + (l & 7) * 8,
                            &As[c * 512]);
            } else {
                const int cb   = c - 8;
                const int rowB = cb * 8 + (l >> 3);
                gload_lds16(Bt + (size_t)(n0 + rowB) * 256 + k0 + (l & 7) * 8,
                            &Bs[cb * 512]);
            }
        }
        __syncthreads();

        #pragma unroll
        for (int kk = 0; kk < 2; ++kk) {
            const int koff = (kk * 64 + (l >> 4) * 16) ^ ((l & 7) << 4);
            bf16x8 af[2], bfr[4];
            #pragma unroll
            for (int mf = 0; mf < 2; ++mf) {
                const int row = wm * 32 + mf * 16 + (l & 15);
                af[mf] = *reinterpret_cast<const bf16x8*>(&As[row * 64 + (koff >> 1)]);
            }
            #pragma unroll
            for (int nf = 0; nf < 4; ++nf) {
                const int row = wn * 64 + nf * 16 + (l & 15);
                bfr[nf] = *reinterpret_cast<const bf16x8*>(&Bs[row * 64 + (koff >> 1)]);
            }
            #pragma unroll
            for (int mf = 0; mf < 2; ++mf)
                #pragma unroll
                for (int nf = 0; nf < 4; ++nf)
                    acc[mf][nf] = __builtin_amdgcn_mfma_f32_16x16x32_bf16(
                        af[mf], bfr[nf], acc[mf][nf], 0, 0, 0);
        }
        __syncthreads();
    }

    float bv[4];
    #pragma unroll
    for (int nf = 0; nf < 4; ++nf)
        bv[nf] = bias[n0 + wn * 64 + nf * 16 + (l & 15)];

    #pragma unroll
    for (int mf = 0; mf < 2; ++mf)
        #pragma unroll
        for (int nf = 0; nf < 4; ++nf) {
            const int col = n0 + wn * 64 + nf * 16 + (l & 15);
            #pragma unroll
            for (int q = 0; q < 4; ++q) {
                const int row = m0 + wm * 32 + mf * 16 + (l >> 4) * 4 + q;
                C[(size_t)row * 256 + col] = acc[mf][nf][q] + bv[nf];
            }
        }
}

// ---------------- fused softmax + deformable sampling (no LDS, no barriers) -------------
// 8 rows/block, 1920 blocks. Phase 1: (r,h,lvl) reads of4/lg4 DIRECTLY from global
// (wave lanes tile each 512B row contiguously -> fully coalesced), computes its
// level's 4 samples into registers. Phase 2: (r,h,d2) pulls {w0,w1,a0,a1} from
// quad-mates via __shfl. Zero LDS, zero barriers.
#define RPB 8

__global__ __launch_bounds__(256) void sample_k(
    const unsigned short* __restrict__ value, // [NB*LIN][256] bf16 linear
    const unsigned short* __restrict__ offbf, // [NROWS][256] bf16 linear
    const float* __restrict__ refp,
    const int*   __restrict__ shapes,
    const int*   __restrict__ starts,
    unsigned short* __restrict__ outbf)       // [NROWS][256] bf16, swizzled rows
{
    const int t  = threadIdx.x;
    const int b0 = blockIdx.x * RPB;
    const int nbase = (b0 / LQ) * LIN;        // block never straddles batch (8 | 3840)

    const int r = t >> 5;          // 0..7
    const int h = (t >> 2) & 7;    // 0..7

    // ---- phase 1: (r,h,lvl) -> this level's 4 samples, kept in registers ----
    float w0r[4], w1r[4];
    int   a0r[4], a1r[4];
    {
        const int lvl = t & 3;
        const int shp = shapes[lvl];
        const int stt = starts[lvl];
        const float T = (float)shp;
        const int Tm1 = shp - 1;
        const size_t rowb = (size_t)(b0 + r) * 256;

        const u16x4 lg4 = *reinterpret_cast<const u16x4*>(
            offbf + rowb + 128 + h * 16 + lvl * 4);
        const u16x4 of4 = *reinterpret_cast<const u16x4*>(
            offbf + rowb + h * 16 + lvl * 4);
        float lg[4], e[4];
        #pragma unroll
        for (int u = 0; u < 4; ++u) lg[u] = bf2f(lg4[u]);

        float mx = fmaxf(fmaxf(lg[0], lg[1]), fmaxf(lg[2], lg[3]));
        mx = fmaxf(mx, __shfl_xor(mx, 1));
        mx = fmaxf(mx, __shfl_xor(mx, 2));
        float sum = 0.f;
        #pragma unroll
        for (int u = 0; u < 4; ++u) { e[u] = __expf(lg[u] - mx); sum += e[u]; }
        sum += __shfl_xor(sum, 1);
        sum += __shfl_xor(sum, 2);
        const float rsum = 1.f / sum;

        const float ref = refp[(size_t)(b0 + r) * NL + lvl];
        #pragma unroll
        for (int u = 0; u < 4; ++u) {
            const float aw  = e[u] * rsum;
            const float off = bf2f(of4[u]);
            const float loc = ref + off / T;     // mimic reference rounding
            const float cc  = loc * T - 0.5f;
            const float fl  = floorf(cc);
            const float wgt = cc - fl;
            const int i0 = (int)fl;
            const int j0 = min(max(i0, 0), Tm1);
            const int j1 = min(max(i0 + 1, 0), Tm1);
            w0r[u] = aw * (1.f - wgt);
            w1r[u] = aw * wgt;
            a0r[u] = nbase + stt + j0;
            a1r[u] = nbase + stt + j1;
        }
    }

    // ---- phase 2: (r,h,d2) -> 8 output dims, 32 gathers of 16B ----
    {
        const int d2    = t & 3;
        const int coff  = h * 32 + d2 * 8;       // ushort offset within value row
        const int lquad = (t & 63) & ~3;         // quad base lane within wave

        float acc[8] = {};
        #pragma unroll
        for (int s = 0; s < 16; ++s) {
            const int src = lquad | (s >> 2);    // quad-mate holding level s>>2
            const float w0 = __shfl(w0r[s & 3], src);
            const float w1 = __shfl(w1r[s & 3], src);
            const int   i0 = __shfl(a0r[s & 3], src);
            const int   i1 = __shfl(a1r[s & 3], src);
            const u16x8 v0 = *reinterpret_cast<const u16x8*>(
                value + (size_t)i0 * 256 + coff);
            const u16x8 v1 = *reinterpret_cast<const u16x8*>(
                value + (size_t)i1 * 256 + coff);
            #pragma unroll
            for (int q = 0; q < 8; ++q)
                acc[q] += w0 * bf2f(v0[q]) + w1 * bf2f(v1[q]);
        }
        const int orow = b0 + r;
        u16x8 o;
        #pragma unroll
        for (int q = 0; q < 8; ++q) o[q] = f2bf(acc[q]);
        const int byte = (h * 64 + d2 * 16) ^ ((orow & 7) << 4);   // within 512B row
        *reinterpret_cast<u16x8*>(&outbf[(size_t)orow * 256 + (byte >> 1)]) = o;
    }
}

extern "C" void kernel_launch(void* const* d_in, const int* in_sizes, int n_in,
                              void* d_out, int out_size, void* d_ws, size_t ws_size,
                              hipStream_t stream) {
    const float* query  = (const float*)d_in[0];
    const float* refp   = (const float*)d_in[1];
    const float* inflat = (const float*)d_in[2];
    const int*   shapes = (const int*)d_in[3];
    const int*   starts = (const int*)d_in[4];
    const float* W_off  = (const float*)d_in[5];
    const float* b_off  = (const float*)d_in[6];
    const float* W_attn = (const float*)d_in[7];
    const float* b_attn = (const float*)d_in[8];
    const float* W_val  = (const float*)d_in[9];
    const float* b_val  = (const float*)d_in[10];
    const float* W_out  = (const float*)d_in[11];
    const float* b_out  = (const float*)d_in[12];
    float* out = (float*)d_out;

    // ws layout
    char* ws = (char*)d_ws;
    const size_t BFMAT = (size_t)NROWS * 256 * 2;    // 7.9 MB
    unsigned short* valbf = (unsigned short*)ws;
    unsigned short* offbf = (unsigned short*)(ws + BFMAT);
    unsigned short* outbf = (unsigned short*)(ws + 2 * BFMAT);
    unsigned short* WvT   = (unsigned short*)(ws + 3 * BFMAT);
    unsigned short* WcT   = WvT + 65536;
    unsigned short* WoutT = WcT + 65536;
    float*          bcat  = (float*)(WoutT + 65536);

    const dim3 blk(256);

    convert_W<<<dim3(16, 3), blk, 0, stream>>>(W_val, W_off, W_attn, W_out, b_off, b_attn,
                                               WvT, WcT, WoutT, bcat);
    // z=0: valbf = inflat@WvT+b_val ; z=1: offbf = query@WcT+bcat   (both bf16)
    gemm_fwd<<<dim3(2, 240, 2), blk, 0, stream>>>(inflat, query, WvT, WcT,
                                                  b_val, bcat, valbf, offbf);
    sample_k<<<NROWS / RPB, blk, 0, stream>>>(valbf, offbf, refp, shapes, starts, outbf);
    gemm_out<<<dim3(2, 240), blk, 0, stream>>>(outbf, WoutT, b_out, out);
}